// Round 5
// baseline (151.530 us; speedup 1.0000x reference)
//
#include <hip/hip_runtime.h>

#define KDIM 64
#define VDIM 64
#define MDIM 2048
#define BDIM 512
#define INDIM 512
#define HDIM 192           // 2K+V
#define CIN 768            // IN + 2K + 2V
#define O_SIZE (BDIM*HDIM) // 98304

// ---------- K1: o = [x, relu(h), content] @ W^T + bias ----------
__global__ __launch_bounds__(512)
void gemm_kernel(const float* __restrict__ x, const float* __restrict__ hidden,
                 const float* __restrict__ content, const float* __restrict__ W,
                 const float* __restrict__ bias, float* __restrict__ out)
{
    const int b   = blockIdx.x;
    const int tid = threadIdx.x;
    __shared__ __align__(16) float inp[CIN];

    inp[tid] = x[(size_t)b*INDIM + tid];                 // 512 threads cover IN
    if (tid < HDIM) inp[INDIM + tid] = fmaxf(hidden[(size_t)b*HDIM + tid], 0.f);
    if (tid < VDIM) inp[INDIM + HDIM + tid] = content[(size_t)b*VDIM + tid];
    __syncthreads();

    if (tid < 2*HDIM) {                                  // 384 active
        const int j    = tid >> 1;
        const int half = tid & 1;
        const float4* w4 = reinterpret_cast<const float4*>(W)
                           + (size_t)j * (CIN/4) + half * (CIN/8);
        const float4* i4 = reinterpret_cast<const float4*>(inp) + half * (CIN/8);
        float ax = 0.f, ay = 0.f, az = 0.f, aw = 0.f;
        #pragma unroll
        for (int r = 0; r < CIN/8; r += 8) {             // 96 float4, 12 rounds
            float4 wr[8];
            #pragma unroll
            for (int u = 0; u < 8; ++u) wr[u] = w4[r + u];
            #pragma unroll
            for (int u = 0; u < 8; ++u) {
                float4 v = i4[r + u];
                ax = fmaf(wr[u].x, v.x, ax);
                ay = fmaf(wr[u].y, v.y, ay);
                az = fmaf(wr[u].z, v.z, az);
                aw = fmaf(wr[u].w, v.w, aw);
            }
        }
        float p = (ax + ay) + (az + aw);
        p += __shfl_xor(p, 1);                           // combine halves
        if (half == 0) out[(size_t)b*HDIM + j] = p + bias[j];
    }
}

// ---------- K2: fused scores+softmax+pv, one 1024-thread block per b ----------
__global__ __launch_bounds__(1024, 8)
void attn_kernel(const float* __restrict__ key_mem,
                 const float* __restrict__ value_mem,
                 const float* __restrict__ o,
                 float* __restrict__ out)
{
    const int b    = blockIdx.x;
    const int tid  = threadIdx.x;
    const int lane = tid & 63;
    const int wid  = tid >> 6;   // 0..15

    __shared__ float q[KDIM];
    __shared__ float red[16];
    __shared__ __align__(16) float attn_lds[MDIM]; // 8 KB

    if (tid < KDIM) q[tid] = o[(size_t)b*HDIM + tid];
    __syncthreads();

    // ---- scores: thread owns float2 of m (1024 threads cover 2048 m) ----
    const float2* km2 = reinterpret_cast<const float2*>(key_mem)
                        + (size_t)b * KDIM * (MDIM/2) + tid;
    float sx = 0.f, sy = 0.f;
    #pragma unroll
    for (int k0 = 0; k0 < KDIM; k0 += 8) {
        float2 kk[8];
        #pragma unroll
        for (int u = 0; u < 8; ++u)
            kk[u] = km2[(size_t)(k0 + u) * (MDIM/2)];
        #pragma unroll
        for (int u = 0; u < 8; ++u) {
            float qk = q[k0 + u];
            sx = fmaf(qk, kk[u].x, sx);
            sy = fmaf(qk, kk[u].y, sy);
        }
    }

    // ---- softmax (16-wave block reduce) ----
    float mx = fmaxf(sx, sy);
    #pragma unroll
    for (int off = 32; off >= 1; off >>= 1) mx = fmaxf(mx, __shfl_xor(mx, off));
    if (lane == 0) red[wid] = mx;
    __syncthreads();
    float m_all = red[0];
    #pragma unroll
    for (int w = 1; w < 16; ++w) m_all = fmaxf(m_all, red[w]);

    float ex = __expf(sx - m_all);
    float ey = __expf(sy - m_all);
    float sum = ex + ey;
    #pragma unroll
    for (int off = 32; off >= 1; off >>= 1) sum += __shfl_xor(sum, off);
    __syncthreads();                  // red(max) consumed
    if (lane == 0) red[wid] = sum;
    __syncthreads();
    float total = 0.f;
    #pragma unroll
    for (int w = 0; w < 16; ++w) total += red[w];
    float inv = 1.0f / total;

    reinterpret_cast<float2*>(attn_lds)[tid] = make_float2(ex*inv, ey*inv);
    __syncthreads();

    // ---- pv: wave handles 4 v's; coalesced float4 value loads ----
    const float4* vm4 = reinterpret_cast<const float4*>(value_mem)
                        + (size_t)b * VDIM * (MDIM/4);
    const float4* a4  = reinterpret_cast<const float4*>(attn_lds);
    #pragma unroll
    for (int vi = 0; vi < 4; ++vi) {
        const int v = wid*4 + vi;
        float4 vv[8];
        #pragma unroll
        for (int i = 0; i < 8; ++i)
            vv[i] = vm4[(size_t)v*(MDIM/4) + i*64 + lane];
        float px = 0.f, py = 0.f, pz = 0.f, pw = 0.f;
        #pragma unroll
        for (int i = 0; i < 8; ++i) {
            float4 aa = a4[i*64 + lane];
            px = fmaf(vv[i].x, aa.x, px);
            py = fmaf(vv[i].y, aa.y, py);
            pz = fmaf(vv[i].z, aa.z, pz);
            pw = fmaf(vv[i].w, aa.w, pw);
        }
        float p = (px + py) + (pz + pw);
        #pragma unroll
        for (int off = 32; off >= 1; off >>= 1) p += __shfl_xor(p, off);
        if (lane == 0) out[O_SIZE + (size_t)b*VDIM + v] = p;
    }
}

extern "C" void kernel_launch(void* const* d_in, const int* in_sizes, int n_in,
                              void* d_out, int out_size, void* d_ws, size_t ws_size,
                              hipStream_t stream) {
    const float* x         = (const float*)d_in[0];
    const float* hidden    = (const float*)d_in[1];
    const float* content   = (const float*)d_in[2];
    const float* key_mem   = (const float*)d_in[3];
    const float* value_mem = (const float*)d_in[4];
    const float* W         = (const float*)d_in[5];
    const float* bias      = (const float*)d_in[6];
    float* out = (float*)d_out;

    gemm_kernel<<<dim3(BDIM), dim3(512),  0, stream>>>(x, hidden, content, W, bias, out);
    attn_kernel<<<dim3(BDIM), dim3(1024), 0, stream>>>(key_mem, value_mem, out, out);
}